// Round 1
// 181.738 us; speedup vs baseline: 1.0059x; 1.0059x over previous
//
#include <hip/hip_runtime.h>

#define HW 32
#define NPIX 1024      // 32*32
#define IMG 3072       // 3*32*32

// ---------------- threefry2x32 (exact JAX semantics) ----------------
__device__ __forceinline__ unsigned rotl32(unsigned x, int d) {
    return (x << d) | (x >> (32 - d));
}

struct UPair { unsigned a, b; };

__device__ __forceinline__ UPair threefry2x32(unsigned k0, unsigned k1,
                                              unsigned x0, unsigned x1) {
    unsigned k2 = k0 ^ k1 ^ 0x1BD11BDAu;
    x0 += k0; x1 += k1;
#define RND(r) { x0 += x1; x1 = rotl32(x1, (r)); x1 ^= x0; }
    RND(13) RND(15) RND(26) RND(6)
    x0 += k1; x1 += k2 + 1u;
    RND(17) RND(29) RND(16) RND(24)
    x0 += k2; x1 += k0 + 2u;
    RND(13) RND(15) RND(26) RND(6)
    x0 += k0; x1 += k1 + 3u;
    RND(17) RND(29) RND(16) RND(24)
    x0 += k1; x1 += k2 + 4u;
    RND(13) RND(15) RND(26) RND(6)
    x0 += k2; x1 += k0 + 5u;
#undef RND
    return {x0, x1};
}

__device__ __forceinline__ float bits_to_u01(unsigned bits) {
    return __uint_as_float((bits >> 9) | 0x3f800000u) - 1.0f;
}

// reference _reflect with lo=-0.5, span=32 — fmod-free.
// For t>=0: mod(t,32) == t - 32*floor(t*(1/32))   (exact: pow-2 scale,
// exact product; identical to JAX's floor-mod lowering). Parity of the
// integer-valued `flips` via int cast instead of a second fmod.
__device__ __forceinline__ float reflect32(float c) {
    float t = fabsf(c + 0.5f);
    float flips = floorf(t * 0.03125f);
    float extra = fmaf(flips, -32.0f, t);
    float o = (((int)flips) & 1) ? (31.5f - extra) : (extra - 0.5f);
    return fminf(fmaxf(o, 0.0f), 31.0f);
}

__global__ __launch_bounds__(256) void aug_kernel(
    const float* __restrict__ xin, const float* __restrict__ aff,
    const int* __restrict__ apply_crop, float* __restrict__ out, int B) {
    __shared__ __align__(16) float bufA[IMG];
    __shared__ __align__(16) float bufB[IMG];
    __shared__ float s_theta[6];
    __shared__ int s_j0[32];     // crop-resize index table (shared row/col)
    __shared__ float s_fr[32];   // crop-resize fraction table
    __shared__ int s_top, s_left, s_flip, s_hue, s_gray, s_blur, s_solar;
    __shared__ float s_bright, s_contr, s_sat;

    const int b = blockIdx.x;
    const int t = threadIdx.x;
    const bool do_crop = (apply_crop[0] != 0);

    const float MEANc[3] = {0.5071f, 0.4867f, 0.4408f};
    const float STDc[3]  = {0.2675f, 0.2565f, 0.2761f};
    const float INVSTD[3] = {1.0f / 0.2675f, 1.0f / 0.2565f, 1.0f / 0.2761f};

    // ---- issue global image loads early ----
    const float4* imgv = (const float4*)(xin + (size_t)b * IMG);
    float4 ld0 = imgv[t];
    float4 ld1 = imgv[t + 256];
    float4 ld2 = imgv[t + 512];

    const size_t OUT_IMG = (size_t)B * IMG;
    if (t < 6) {  // theta into LDS + affine passthrough output
        float v = aff[b * 6 + t];
        s_theta[t] = v;
        out[OUT_IMG + (size_t)B + (size_t)b * 6 + t] = v;
    }

    // ---- crop-resize index/frac table (same function for rows and cols) ----
    if (t < 32) {
        float d = fmaxf(((float)t + 0.5f) * 0.78125f - 0.5f, 0.0f);
        int j0 = (int)d;
        s_j0[t] = j0;
        s_fr[t] = d - (float)j0;
    }

    // ---- per-image RNG (jax_threefry_partitionable=True semantics) ----
    // ks = split(key(42), 10): ks[k] = threefry(0,42, 0,k) full pair.
    // random_bits(key,32,(B,)): bits[b] = r.a ^ r.b, r = threefry(key, 0, b).
    // randint: _split(key) -> k2 = threefry(key,0,1) pair; val = bits(k2,b) & 7.
    if (t < 10) {
        int k = t;
        UPair K = threefry2x32(0u, 42u, 0u, (unsigned)k);  // ks[k]
        if (k < 2) {
            UPair k2 = threefry2x32(K.a, K.b, 0u, 1u);     // lower-bits child key
            UPair r = threefry2x32(k2.a, k2.b, 0u, (unsigned)b);
            int val = (int)((r.a ^ r.b) & 7u);
            if (k == 0) s_top = val; else s_left = val;
        } else {
            UPair r = threefry2x32(K.a, K.b, 0u, (unsigned)b);
            float u = bits_to_u01(r.a ^ r.b);
            if      (k == 2) s_flip  = (u < 0.5f);
            else if (k == 3) s_bright = 1.0f + (u - 0.5f) * 0.8f;
            else if (k == 4) s_contr  = 1.0f + (u - 0.5f) * 0.8f;
            else if (k == 5) s_sat    = 1.0f + (u - 0.5f) * 0.8f;
            else if (k == 6) s_hue   = (u < 0.5f);
            else if (k == 7) s_gray  = (u < 0.2f);
            else if (k == 8) s_blur  = (u < 0.5f);
            else             s_solar = (u < 0.1f);
        }
    }

    // ---- denormalize + stage into LDS ----
    {
        float4 v = ld0;
        v.x = v.x * STDc[0] + MEANc[0]; v.y = v.y * STDc[0] + MEANc[0];
        v.z = v.z * STDc[0] + MEANc[0]; v.w = v.w * STDc[0] + MEANc[0];
        ((float4*)bufA)[t] = v;
        v = ld1;
        v.x = v.x * STDc[1] + MEANc[1]; v.y = v.y * STDc[1] + MEANc[1];
        v.z = v.z * STDc[1] + MEANc[1]; v.w = v.w * STDc[1] + MEANc[1];
        ((float4*)bufA)[t + 256] = v;
        v = ld2;
        v.x = v.x * STDc[2] + MEANc[2]; v.y = v.y * STDc[2] + MEANc[2];
        v.z = v.z * STDc[2] + MEANc[2]; v.w = v.w * STDc[2] + MEANc[2];
        ((float4*)bufA)[t + 512] = v;
    }
    __syncthreads();

    if (t == 0) out[OUT_IMG + b] = s_flip ? 1.0f : 0.0f;

    float* cur = bufA;
    float* nxt = bufB;

    // ---- crop-resize (block-uniform branch, table-driven indices) ----
    if (do_crop) {
        const int top = s_top, left = s_left;
#pragma unroll
        for (int m = 0; m < 4; ++m) {
            int s = t + 256 * m;
            int yi = s >> 5, xj = s & 31;
            int i0 = s_j0[yi]; float ly = s_fr[yi];   // broadcast within row group
            int q0 = s_j0[xj]; float lx = s_fr[xj];   // stride-1, conflict-free
            int i1 = min(i0 + 1, 24);
            int q1 = min(q0 + 1, 24);
            int r0 = (top + i0) << 5, r1 = (top + i1) << 5;
            int c0 = left + q0, c1 = left + q1;
            float omy = 1.0f - ly, omx = 1.0f - lx;
            float w00 = omy * omx, w01 = omy * lx;
            float w10 = ly * omx, w11 = ly * lx;
            int a00 = r0 + c0, a01 = r0 + c1, a10 = r1 + c0, a11 = r1 + c1;
#pragma unroll
            for (int c = 0; c < 3; ++c) {
                const float* p = cur + c * NPIX;
                nxt[c * NPIX + s] = fmaf(p[a00], w00, fmaf(p[a01], w01,
                                    fmaf(p[a10], w10, p[a11] * w11)));
            }
        }
        float* tp = cur; cur = nxt; nxt = tp;
        __syncthreads();
    }

    // ---- grid sample (flip folded into column index) + fused color chain ----
    {
        const int flip = s_flip, hue = s_hue, grayf = s_gray;
        const float br = s_bright;
        const float ctsa = s_contr * s_sat;   // contrast preserves the mean,
                                              // so contrast∘saturation fuses
        const float th0 = s_theta[0], th1 = s_theta[1], th2 = s_theta[2];
        const float th3 = s_theta[3], th4 = s_theta[4], th5 = s_theta[5];
#pragma unroll
        for (int m = 0; m < 4; ++m) {
            int s = t + 256 * m;
            int yi = s >> 5, xj = s & 31;
            float xn = (float)xj * 0.0625f - 0.96875f;   // (xj+0.5)/16 - 1
            float yn = (float)yi * 0.0625f - 0.96875f;
            float gx = fmaf(th0, xn, fmaf(th1, yn, th2));
            float gy = fmaf(th3, xn, fmaf(th4, yn, th5));
            float ix = reflect32(fmaf(gx, 16.0f, 15.5f)); // ((g+1)*32-1)*0.5
            float iy = reflect32(fmaf(gy, 16.0f, 15.5f));
            float fy = floorf(iy), fx = floorf(ix);
            float wy = iy - fy, wx = ix - fx;
            int y0 = (int)fy; int y1 = min(y0 + 1, 31);   // iy∈[0,31] ⇒ no lo-clamp
            int x0 = (int)fx; int x1 = min(x0 + 1, 31);
            if (flip) { x0 = 31 - x0; x1 = 31 - x1; }
            int r0 = y0 << 5, r1 = y1 << 5;
            float omy = 1.0f - wy, omx = 1.0f - wx;
            float w00 = omy * omx, w01 = omy * wx;
            float w10 = wy * omx, w11 = wy * wx;
            int a00 = r0 + x0, a01 = r0 + x1, a10 = r1 + x0, a11 = r1 + x1;
            float ch0, ch1, ch2;
            {
                const float* p = cur;
                ch0 = fmaf(p[a00], w00, fmaf(p[a01], w01,
                       fmaf(p[a10], w10, p[a11] * w11)));
            }
            {
                const float* p = cur + NPIX;
                ch1 = fmaf(p[a00], w00, fmaf(p[a01], w01,
                       fmaf(p[a10], w10, p[a11] * w11)));
            }
            {
                const float* p = cur + 2 * NPIX;
                ch2 = fmaf(p[a00], w00, fmaf(p[a01], w01,
                       fmaf(p[a10], w10, p[a11] * w11)));
            }
            // brightness
            ch0 *= br; ch1 *= br; ch2 *= br;
            // contrast + saturation fused (single mean; both preserve it)
            float g = (ch0 + ch1 + ch2) * (1.0f / 3.0f);
            ch0 = fmaf(ch0 - g, ctsa, g);
            ch1 = fmaf(ch1 - g, ctsa, g);
            ch2 = fmaf(ch2 - g, ctsa, g);
            // hue: channel reverse (mean-invariant, so gray can still use g)
            if (hue) { float tmp = ch0; ch0 = ch2; ch2 = tmp; }
            // grayscale
            if (grayf) { ch0 = ch1 = ch2 = g; }
            nxt[s] = ch0; nxt[NPIX + s] = ch1; nxt[2 * NPIX + s] = ch2;
        }
        float* tp = cur; cur = nxt; nxt = tp;
        __syncthreads();
    }

    const int blur = s_blur, solar = s_solar;

    // ---- separable blur: horizontal 3-tap into the free buffer ----
    if (blur) {
#pragma unroll
        for (int m = 0; m < 4; ++m) {
            int s = t + 256 * m;
            int yi = s >> 5, xj = s & 31;
            int yc = yi << 5;
            int xm = max(xj - 1, 0), xp = min(xj + 1, 31);
#pragma unroll
            for (int c = 0; c < 3; ++c) {
                const float* p = cur + c * NPIX;
                nxt[c * NPIX + s] = p[yc + xm] + p[yc + xj] + p[yc + xp];
            }
        }
        __syncthreads();
    }

    // ---- vertical blur / passthrough + solarize + clip + renorm + store ----
    {
        float* o = out + (size_t)b * IMG;
#pragma unroll
        for (int m = 0; m < 4; ++m) {
            int s = t + 256 * m;
            int yi = s >> 5, xj = s & 31;
            int ym = max(yi - 1, 0) << 5, yp = min(yi + 1, 31) << 5;
#pragma unroll
            for (int c = 0; c < 3; ++c) {
                float r;
                if (blur) {
                    const float* h = nxt + c * NPIX;
                    r = (h[ym + xj] + h[s] + h[yp + xj]) * (1.0f / 9.0f);
                } else {
                    r = cur[c * NPIX + s];
                }
                if (solar && r > 0.5f) r = 1.0f - r;
                r = fminf(fmaxf(r, 0.0f), 1.0f);
                r = (r - MEANc[c]) * INVSTD[c];
                o[c * NPIX + s] = r;
            }
        }
    }
}

extern "C" void kernel_launch(void* const* d_in, const int* in_sizes, int n_in,
                              void* d_out, int out_size, void* d_ws, size_t ws_size,
                              hipStream_t stream) {
    const float* x = (const float*)d_in[0];
    const float* aff = (const float*)d_in[1];
    const int* ac = (const int*)d_in[2];
    float* out = (float*)d_out;
    int B = in_sizes[0] / IMG;
    aug_kernel<<<dim3(B), dim3(256), 0, stream>>>(x, aff, ac, out, B);
}